// Round 1
// baseline (550.052 us; speedup 1.0000x reference)
//
#include <hip/hip_runtime.h>

// ---------------------------------------------------------------------------
// Attention_49185965474367: B=4, N=1024, D=1024, H=16, DH=64, INNER=1024
// R3: attn reads K/V fragments directly from L2 (no LDS staging, ZERO barriers
//     in the K-loop), XCD-swizzled so each XCD's 128 resident blocks share
//     8 bh (2 MB < 4 MB L2). GEMMs unchanged (m97 structure).
// ---------------------------------------------------------------------------

#define NEGMAX 3.402823466e+38f

typedef short short8 __attribute__((ext_vector_type(8)));
typedef float f32x4 __attribute__((ext_vector_type(4)));

__device__ __forceinline__ unsigned short f2bf(float f) {
  unsigned int u = __float_as_uint(f);
  u += 0x7FFFu + ((u >> 16) & 1u);   // round-to-nearest-even
  return (unsigned short)(u >> 16);
}

// async global->LDS, 16B per lane. lds_base must be wave-uniform; HW scatters
// lane i to lds_base + i*16 (guide §5; padding-free layouts only).
__device__ __forceinline__ void stage16(const void* g, void* lds_base, int lane) {
#if __has_builtin(__builtin_amdgcn_global_load_lds)
  __builtin_amdgcn_global_load_lds(
      (const __attribute__((address_space(1))) unsigned int*)g,
      (__attribute__((address_space(3))) unsigned int*)lds_base, 16, 0, 0);
#else
  *(int4*)((char*)lds_base + lane * 16) = *(const int4*)g;
#endif
}

// ---------------- cast kernels ---------------------------------------------
__global__ void cast_x_k(const float* __restrict__ x, unsigned short* __restrict__ xb) {
  int i = (blockIdx.x * 256 + threadIdx.x) * 4;
  float4 v = *(const float4*)(x + i);
  ushort4 o;
  o.x = f2bf(v.x); o.y = f2bf(v.y); o.z = f2bf(v.z); o.w = f2bf(v.w);
  *(ushort4*)(xb + i) = o;
}

// dst[n][d] = src[d][n]  (src fp32 [1024 x ldsrc], dst bf16 rows of 1024)
__global__ __launch_bounds__(256) void tcast_k(const float* __restrict__ src, int ldsrc,
                                               unsigned short* __restrict__ dst) {
  __shared__ float T[64][65];
  const int n0 = blockIdx.x * 64, d0 = blockIdx.y * 64;
  const int tx = threadIdx.x & 63, ty = threadIdx.x >> 6;
#pragma unroll
  for (int k = 0; k < 16; ++k) {
    int dl = k * 4 + ty;
    T[dl][tx] = src[(size_t)(d0 + dl) * ldsrc + n0 + tx];
  }
  __syncthreads();
#pragma unroll
  for (int k = 0; k < 16; ++k) {
    int nl = k * 4 + ty;
    dst[(size_t)(n0 + nl) * 1024 + d0 + tx] = f2bf(T[tx][nl]);
  }
}

// ---------------- GEMM: C[M,N] = A[M,K] @ Bt[N,K]^T  (bf16 in, fp32 acc) ---
// 128x128 tile, BK=32, 256 threads (4 waves), global_load_lds staging (m97).
template <int MODE>
__global__ __launch_bounds__(256) void gemm_bt_k(
    const unsigned short* __restrict__ A, const unsigned short* __restrict__ Bt,
    unsigned short* __restrict__ qws, unsigned short* __restrict__ kws,
    unsigned short* __restrict__ vtws,
    const float* __restrict__ bias, float* __restrict__ Cout) {
  constexpr int K = 1024;
  constexpr int NKB = K / 32;
  __shared__ alignas(16) unsigned short As[128 * 32];
  __shared__ alignas(16) unsigned short Bs[128 * 32];
  const int tid = threadIdx.x;
  const int lane = tid & 63, w = tid >> 6;
  const int quad = lane >> 4, lanelo = lane & 15;
  const int tRow = blockIdx.y * 128, tCol = blockIdx.x * 128;
  const int wr = (w >> 1) * 64, wc = (w & 1) * 64;
  const char* AgB = (const char*)(A + (size_t)tRow * K);
  const char* BgB = (const char*)(Bt + (size_t)tCol * K);
  const int c0 = tid, c1 = tid + 256;
  const size_t a0off = (size_t)(c0 >> 2) * 2048 + (c0 & 3) * 16;
  const size_t a1off = (size_t)(c1 >> 2) * 2048 + (c1 & 3) * 16;
  char* ldsA0 = (char*)As + w * 1024;
  char* ldsA1 = (char*)As + 4096 + w * 1024;
  char* ldsB0 = (char*)Bs + w * 1024;
  char* ldsB1 = (char*)Bs + 4096 + w * 1024;

  f32x4 acc[4][4];
#pragma unroll
  for (int i = 0; i < 4; ++i)
#pragma unroll
    for (int j = 0; j < 4; ++j) acc[i][j] = (f32x4){0.f, 0.f, 0.f, 0.f};

  for (int kb = 0; kb < NKB; ++kb) {
    if (kb) __syncthreads();
    const size_t ko = (size_t)kb * 64;
    stage16(AgB + a0off + ko, ldsA0, lane);
    stage16(AgB + a1off + ko, ldsA1, lane);
    stage16(BgB + a0off + ko, ldsB0, lane);
    stage16(BgB + a1off + ko, ldsB1, lane);
    __syncthreads();   // drains vmcnt before any frag read

    short8 af[4], bf[4];
#pragma unroll
    for (int i = 0; i < 4; ++i)
      af[i] = *(const short8*)(As + (wr + i * 16 + lanelo) * 32 + quad * 8);
#pragma unroll
    for (int j = 0; j < 4; ++j)
      bf[j] = *(const short8*)(Bs + (wc + j * 16 + lanelo) * 32 + quad * 8);
#pragma unroll
    for (int i = 0; i < 4; ++i)
#pragma unroll
      for (int j = 0; j < 4; ++j)
        acc[i][j] = __builtin_amdgcn_mfma_f32_16x16x32_bf16(af[i], bf[j], acc[i][j], 0, 0, 0);
  }

  if (MODE == 0) {
#pragma unroll
    for (int i = 0; i < 4; ++i) {
      int row = tRow + wr + i * 16 + quad * 4;
      int b_ = row >> 10;
      int npos = row & 1023;
#pragma unroll
      for (int j = 0; j < 4; ++j) {
        int col = tCol + wc + j * 16 + lanelo;
        if (col < 2048) {
          unsigned short* dst = (col < 1024) ? qws : kws;
          int c = col & 1023;
          int hh = c >> 6, dh = c & 63;
          size_t base = ((size_t)(b_ * 16 + hh) * 1024 + npos) * 64 + dh;
#pragma unroll
          for (int r = 0; r < 4; ++r) dst[base + (size_t)r * 64] = f2bf(acc[i][j][r]);
        } else {
          int c = col - 2048;
          ushort4 pk;
          pk.x = f2bf(acc[i][j][0]);
          pk.y = f2bf(acc[i][j][1]);
          pk.z = f2bf(acc[i][j][2]);
          pk.w = f2bf(acc[i][j][3]);
          *(ushort4*)&vtws[((size_t)(b_ * 16 + (c >> 6)) * 64 + (c & 63)) * 1024 + npos] = pk;
        }
      }
    }
  } else {
#pragma unroll
    for (int i = 0; i < 4; ++i) {
      int row = tRow + wr + i * 16 + quad * 4;
#pragma unroll
      for (int j = 0; j < 4; ++j) {
        int col = tCol + wc + j * 16 + lanelo;
        float bv = bias[col];
#pragma unroll
        for (int r = 0; r < 4; ++r)
          Cout[(size_t)(row + r) * 1024 + col] = acc[i][j][r] + bv;
      }
    }
  }
}

// ---------------- flash attention, barrier-free K-loop ----------------------
// grid (16, 64) remapped via bijective XCD swizzle: each XCD's 128 resident
// blocks cover 8 bh -> K/V (2 MB) stays L2-resident; fragments read straight
// from global (L2 hit), no Kl/Vl staging, no __syncthreads in the loop.
// q,k: bf16 [bh][n][64]; vt: bf16 [bh][dh][n]; rel fp32 [bh][n][n].
__global__ __launch_bounds__(256, 4) void attn_k(
    const unsigned short* __restrict__ q_ws, const unsigned short* __restrict__ k_ws,
    const unsigned short* __restrict__ vt_ws, const float* __restrict__ rel,
    const int* __restrict__ qmask, const int* __restrict__ cmask,
    unsigned short* __restrict__ aout) {
  constexpr float SCALE = 0.125f;  // 64^-0.5
  __shared__ alignas(16) unsigned short Pl[4 * 16 * 72];
  __shared__ float cml[1024];

  const int tid = threadIdx.x;
  const int w = tid >> 6, lane = tid & 63;
  const int quad = lane >> 4, lanelo = lane & 15;

  // XCD swizzle: flat in [0,1024); virt = (flat%8)*128 + flat/8 (bijective).
  // HW round-robins flat%8 over XCDs -> XCD x owns virt in [x*128,(x+1)*128)
  // = bh in [x*8, x*8+8).
  const int flat = blockIdx.y * 16 + blockIdx.x;
  const int virt = (flat & 7) * 128 + (flat >> 3);
  const int bh = virt >> 4, qblk = virt & 15;
  const int b_ = bh >> 4, h = bh & 15;
  const int qrow0 = qblk * 64 + w * 16;

  for (int i = tid; i < 1024; i += 256)
    cml[i] = (cmask[b_ * 1024 + i] != 0) ? 1.f : 0.f;
  __syncthreads();   // the only block-wide barrier

  const unsigned short* qg = q_ws + ((size_t)bh * 1024 + qrow0) * 64;
  short8 qf0 = *(const short8*)(qg + (size_t)lanelo * 64 + quad * 8);
  short8 qf1 = *(const short8*)(qg + (size_t)lanelo * 64 + 32 + quad * 8);

  float qmv[4];
#pragma unroll
  for (int r = 0; r < 4; ++r)
    qmv[r] = (qmask[b_ * 1024 + qrow0 + quad * 4 + r] != 0) ? 1.f : 0.f;

  f32x4 o[4];
#pragma unroll
  for (int g = 0; g < 4; ++g) o[g] = (f32x4){0.f, 0.f, 0.f, 0.f};
  float m_run[4], l_run[4];
#pragma unroll
  for (int r = 0; r < 4; ++r) { m_run[r] = -NEGMAX; l_run[r] = 0.f; }

  const unsigned short* kg = k_ws + (size_t)bh * 65536;
  const unsigned short* vg = vt_ws + (size_t)bh * 65536;
  const float* relg = rel + ((size_t)bh * 1024 + qrow0) * 1024;
  unsigned short* pw = Pl + w * 16 * 72;

  for (int kb = 0; kb < 16; ++kb) {
    const int key0 = kb * 64;

    // S = Q K^T : 16 q-rows x 64 keys; K fragments straight from L2.
    f32x4 s[4];
#pragma unroll
    for (int c = 0; c < 4; ++c) {
      const unsigned short* krow = kg + (size_t)(key0 + c * 16 + lanelo) * 64;
      short8 kfa = *(const short8*)(krow + quad * 8);
      short8 kfb = *(const short8*)(krow + 32 + quad * 8);
      s[c] = (f32x4){0.f, 0.f, 0.f, 0.f};
      s[c] = __builtin_amdgcn_mfma_f32_16x16x32_bf16(qf0, kfa, s[c], 0, 0, 0);
      s[c] = __builtin_amdgcn_mfma_f32_16x16x32_bf16(qf1, kfb, s[c], 0, 0, 0);
    }

    // rel (fp32, streams from HBM) + context mask
    float rl[4][4];
#pragma unroll
    for (int r = 0; r < 4; ++r)
#pragma unroll
      for (int c = 0; c < 4; ++c)
        rl[r][c] = relg[(size_t)(quad * 4 + r) * 1024 + key0 + c * 16 + lanelo];
    float cm[4];
#pragma unroll
    for (int c = 0; c < 4; ++c) cm[c] = cml[key0 + c * 16 + lanelo];

#pragma unroll
    for (int r = 0; r < 4; ++r) {
      const bool qok = qmv[r] != 0.f;
      float x[4], mloc = -NEGMAX;
#pragma unroll
      for (int c = 0; c < 4; ++c) {
        x[c] = (qok && cm[c] != 0.f) ? s[c][r] * SCALE + rl[r][c] : -NEGMAX;
        mloc = fmaxf(mloc, x[c]);
      }
      for (int off = 1; off < 16; off <<= 1) mloc = fmaxf(mloc, __shfl_xor(mloc, off));
      float mnew = fmaxf(m_run[r], mloc);
      float alpha = __expf(m_run[r] - mnew);
      m_run[r] = mnew;
      float ps = 0.f;
      unsigned short pb[4];
#pragma unroll
      for (int c = 0; c < 4; ++c) {
        float p = __expf(x[c] - mnew);
        ps += p;
        pb[c] = f2bf(p);
      }
      for (int off = 1; off < 16; off <<= 1) ps += __shfl_xor(ps, off);
      l_run[r] = l_run[r] * alpha + ps;
#pragma unroll
      for (int g = 0; g < 4; ++g) o[g][r] *= alpha;
#pragma unroll
      for (int c = 0; c < 4; ++c) pw[(quad * 4 + r) * 72 + c * 16 + lanelo] = pb[c];
    }

    // P (A-layout via per-wave LDS transpose; within-wave, no barrier needed)
    // @ V, V fragments straight from L2, two k=32 chunks.
#pragma unroll
    for (int c2 = 0; c2 < 2; ++c2) {
      short8 pa = *(const short8*)((const char*)pw + lanelo * 144 + c2 * 64 + quad * 16);
#pragma unroll
      for (int g = 0; g < 4; ++g) {
        short8 vb = *(const short8*)(vg + (size_t)(g * 16 + lanelo) * 1024 + key0 + c2 * 32 + quad * 8);
        o[g] = __builtin_amdgcn_mfma_f32_16x16x32_bf16(pa, vb, o[g], 0, 0, 0);
      }
    }
  }

#pragma unroll
  for (int r = 0; r < 4; ++r) {
    float inv = 1.f / l_run[r];
    size_t row = (size_t)(b_ * 1024 + qrow0 + quad * 4 + r) * 1024;
#pragma unroll
    for (int g = 0; g < 4; ++g)
      aout[row + h * 64 + g * 16 + lanelo] = f2bf(o[g][r] * inv);
  }
}

// ---------------- launch ----------------------------------------------------
extern "C" void kernel_launch(void* const* d_in, const int* in_sizes, int n_in,
                              void* d_out, int out_size, void* d_ws, size_t ws_size,
                              hipStream_t stream) {
  const float* x = (const float*)d_in[0];
  const float* rel = (const float*)d_in[1];
  const int* qmask = (const int*)d_in[2];
  const int* cmask = (const int*)d_in[3];
  const float* Wq = (const float*)d_in[4];
  const float* Wkv = (const float*)d_in[5];
  const float* Wo = (const float*)d_in[6];
  const float* bo = (const float*)d_in[7];
  float* out = (float*)d_out;

  char* ws = (char*)d_ws;
  const size_t MB = 1024 * 1024;
  unsigned short* w3t = (unsigned short*)(ws);            // 3072x1024 bf16 (6 MB)
  unsigned short* wot = (unsigned short*)(ws + 6 * MB);   // 1024x1024 bf16 (2 MB)
  unsigned short* xb  = (unsigned short*)(ws + 8 * MB);   // 4096x1024 bf16 (8 MB)
  unsigned short* qws = (unsigned short*)(ws + 16 * MB);  // [bh][n][64] (8 MB)
  unsigned short* kws = (unsigned short*)(ws + 24 * MB);  // 8 MB
  unsigned short* vtws = (unsigned short*)(ws + 32 * MB); // [bh][dh][n] (8 MB)
  unsigned short* aout = xb;  // reuse: x dead after QKV GEMM

  cast_x_k<<<4096, 256, 0, stream>>>(x, xb);
  tcast_k<<<dim3(16, 16), 256, 0, stream>>>(Wq, 1024, w3t);
  tcast_k<<<dim3(32, 16), 256, 0, stream>>>(Wkv, 2048, w3t + (size_t)1024 * 1024);
  tcast_k<<<dim3(16, 16), 256, 0, stream>>>(Wo, 1024, wot);
  gemm_bt_k<0><<<dim3(24, 32), 256, 0, stream>>>(xb, w3t, qws, kws, vtws, nullptr, nullptr);
  attn_k<<<dim3(16, 64), 256, 0, stream>>>(qws, kws, vtws, rel, qmask, cmask, aout);
  gemm_bt_k<1><<<dim3(8, 32), 256, 0, stream>>>(aout, wot, nullptr, nullptr, nullptr, bo, out);
}

// Round 2
// 521.586 us; speedup vs baseline: 1.0546x; 1.0546x over previous
//
#include <hip/hip_runtime.h>

// ---------------------------------------------------------------------------
// Attention_49185965474367: B=4, N=1024, D=1024, H=16, DH=64, INNER=1024
// R4: attn = barrier-free K-loop (R3) + rel register prefetch (R2) restored.
//     gemm1 retiled to 64x64 (1024 blocks = 4/CU) to fix 1-block/CU occupancy.
// ---------------------------------------------------------------------------

#define NEGMAX 3.402823466e+38f

typedef short short8 __attribute__((ext_vector_type(8)));
typedef float f32x4 __attribute__((ext_vector_type(4)));

__device__ __forceinline__ unsigned short f2bf(float f) {
  unsigned int u = __float_as_uint(f);
  u += 0x7FFFu + ((u >> 16) & 1u);   // round-to-nearest-even
  return (unsigned short)(u >> 16);
}

// async global->LDS, 16B per lane. lds_base must be wave-uniform; HW scatters
// lane i to lds_base + i*16 (guide §5; padding-free layouts only).
__device__ __forceinline__ void stage16(const void* g, void* lds_base, int lane) {
#if __has_builtin(__builtin_amdgcn_global_load_lds)
  __builtin_amdgcn_global_load_lds(
      (const __attribute__((address_space(1))) unsigned int*)g,
      (__attribute__((address_space(3))) unsigned int*)lds_base, 16, 0, 0);
#else
  *(int4*)((char*)lds_base + lane * 16) = *(const int4*)g;
#endif
}

// ---------------- cast kernels ---------------------------------------------
__global__ void cast_x_k(const float* __restrict__ x, unsigned short* __restrict__ xb) {
  int i = (blockIdx.x * 256 + threadIdx.x) * 4;
  float4 v = *(const float4*)(x + i);
  ushort4 o;
  o.x = f2bf(v.x); o.y = f2bf(v.y); o.z = f2bf(v.z); o.w = f2bf(v.w);
  *(ushort4*)(xb + i) = o;
}

// dst[n][d] = src[d][n]  (src fp32 [1024 x ldsrc], dst bf16 rows of 1024)
__global__ __launch_bounds__(256) void tcast_k(const float* __restrict__ src, int ldsrc,
                                               unsigned short* __restrict__ dst) {
  __shared__ float T[64][65];
  const int n0 = blockIdx.x * 64, d0 = blockIdx.y * 64;
  const int tx = threadIdx.x & 63, ty = threadIdx.x >> 6;
#pragma unroll
  for (int k = 0; k < 16; ++k) {
    int dl = k * 4 + ty;
    T[dl][tx] = src[(size_t)(d0 + dl) * ldsrc + n0 + tx];
  }
  __syncthreads();
#pragma unroll
  for (int k = 0; k < 16; ++k) {
    int nl = k * 4 + ty;
    dst[(size_t)(n0 + nl) * 1024 + d0 + tx] = f2bf(T[tx][nl]);
  }
}

// ---------------- GEMM: C[M,N] = A[M,K] @ Bt[N,K]^T  (bf16 in, fp32 acc) ---
// 128x128 tile, BK=32, 256 threads (4 waves), global_load_lds staging (m97).
// MODE 0 only (QKV projection with scattered head-layout epilogue).
__global__ __launch_bounds__(256) void gemm_bt_k(
    const unsigned short* __restrict__ A, const unsigned short* __restrict__ Bt,
    unsigned short* __restrict__ qws, unsigned short* __restrict__ kws,
    unsigned short* __restrict__ vtws) {
  constexpr int K = 1024;
  constexpr int NKB = K / 32;
  __shared__ alignas(16) unsigned short As[128 * 32];
  __shared__ alignas(16) unsigned short Bs[128 * 32];
  const int tid = threadIdx.x;
  const int lane = tid & 63, w = tid >> 6;
  const int quad = lane >> 4, lanelo = lane & 15;
  const int tRow = blockIdx.y * 128, tCol = blockIdx.x * 128;
  const int wr = (w >> 1) * 64, wc = (w & 1) * 64;
  const char* AgB = (const char*)(A + (size_t)tRow * K);
  const char* BgB = (const char*)(Bt + (size_t)tCol * K);
  const int c0 = tid, c1 = tid + 256;
  const size_t a0off = (size_t)(c0 >> 2) * 2048 + (c0 & 3) * 16;
  const size_t a1off = (size_t)(c1 >> 2) * 2048 + (c1 & 3) * 16;
  char* ldsA0 = (char*)As + w * 1024;
  char* ldsA1 = (char*)As + 4096 + w * 1024;
  char* ldsB0 = (char*)Bs + w * 1024;
  char* ldsB1 = (char*)Bs + 4096 + w * 1024;

  f32x4 acc[4][4];
#pragma unroll
  for (int i = 0; i < 4; ++i)
#pragma unroll
    for (int j = 0; j < 4; ++j) acc[i][j] = (f32x4){0.f, 0.f, 0.f, 0.f};

  for (int kb = 0; kb < NKB; ++kb) {
    if (kb) __syncthreads();
    const size_t ko = (size_t)kb * 64;
    stage16(AgB + a0off + ko, ldsA0, lane);
    stage16(AgB + a1off + ko, ldsA1, lane);
    stage16(BgB + a0off + ko, ldsB0, lane);
    stage16(BgB + a1off + ko, ldsB1, lane);
    __syncthreads();   // drains vmcnt before any frag read

    short8 af[4], bf[4];
#pragma unroll
    for (int i = 0; i < 4; ++i)
      af[i] = *(const short8*)(As + (wr + i * 16 + lanelo) * 32 + quad * 8);
#pragma unroll
    for (int j = 0; j < 4; ++j)
      bf[j] = *(const short8*)(Bs + (wc + j * 16 + lanelo) * 32 + quad * 8);
#pragma unroll
    for (int i = 0; i < 4; ++i)
#pragma unroll
      for (int j = 0; j < 4; ++j)
        acc[i][j] = __builtin_amdgcn_mfma_f32_16x16x32_bf16(af[i], bf[j], acc[i][j], 0, 0, 0);
  }

#pragma unroll
  for (int i = 0; i < 4; ++i) {
    int row = tRow + wr + i * 16 + quad * 4;
    int b_ = row >> 10;
    int npos = row & 1023;
#pragma unroll
    for (int j = 0; j < 4; ++j) {
      int col = tCol + wc + j * 16 + lanelo;
      if (col < 2048) {
        unsigned short* dst = (col < 1024) ? qws : kws;
        int c = col & 1023;
        int hh = c >> 6, dh = c & 63;
        size_t base = ((size_t)(b_ * 16 + hh) * 1024 + npos) * 64 + dh;
#pragma unroll
        for (int r = 0; r < 4; ++r) dst[base + (size_t)r * 64] = f2bf(acc[i][j][r]);
      } else {
        int c = col - 2048;
        ushort4 pk;
        pk.x = f2bf(acc[i][j][0]);
        pk.y = f2bf(acc[i][j][1]);
        pk.z = f2bf(acc[i][j][2]);
        pk.w = f2bf(acc[i][j][3]);
        *(ushort4*)&vtws[((size_t)(b_ * 16 + (c >> 6)) * 64 + (c & 63)) * 1024 + npos] = pk;
      }
    }
  }
}

// ---------------- GEMM 64x64: C = A @ Bt^T + bias  (out projection) --------
// 1024 blocks (4/CU), 256 thr = 4 waves; wave w owns rows [w*16, w*16+16).
__global__ __launch_bounds__(256) void gemm64_k(
    const unsigned short* __restrict__ A, const unsigned short* __restrict__ Bt,
    const float* __restrict__ bias, float* __restrict__ Cout) {
  constexpr int K = 1024;
  constexpr int NKB = K / 32;
  __shared__ alignas(16) unsigned short As[64 * 32];
  __shared__ alignas(16) unsigned short Bs[64 * 32];
  const int tid = threadIdx.x;
  const int lane = tid & 63, w = tid >> 6;
  const int quad = lane >> 4, lanelo = lane & 15;
  const int tRow = blockIdx.y * 64, tCol = blockIdx.x * 64;
  const char* AgB = (const char*)(A + (size_t)tRow * K);
  const char* BgB = (const char*)(Bt + (size_t)tCol * K);
  // chunk c = tid: row = c>>2 (0..63), 16B piece (c&3); row stride 2048B.
  const size_t aoff = (size_t)(tid >> 2) * 2048 + (tid & 3) * 16;
  char* ldsA = (char*)As + w * 1024;
  char* ldsB = (char*)Bs + w * 1024;

  f32x4 acc[4];
#pragma unroll
  for (int j = 0; j < 4; ++j) acc[j] = (f32x4){0.f, 0.f, 0.f, 0.f};

  for (int kb = 0; kb < NKB; ++kb) {
    if (kb) __syncthreads();
    const size_t ko = (size_t)kb * 64;
    stage16(AgB + aoff + ko, ldsA, lane);
    stage16(BgB + aoff + ko, ldsB, lane);
    __syncthreads();

    short8 af = *(const short8*)(As + (w * 16 + lanelo) * 32 + quad * 8);
#pragma unroll
    for (int j = 0; j < 4; ++j) {
      short8 bf = *(const short8*)(Bs + (j * 16 + lanelo) * 32 + quad * 8);
      acc[j] = __builtin_amdgcn_mfma_f32_16x16x32_bf16(af, bf, acc[j], 0, 0, 0);
    }
  }

  const int row = tRow + w * 16 + quad * 4;
#pragma unroll
  for (int j = 0; j < 4; ++j) {
    int col = tCol + j * 16 + lanelo;
    float bv = bias[col];
#pragma unroll
    for (int r = 0; r < 4; ++r)
      Cout[(size_t)(row + r) * 1024 + col] = acc[j][r] + bv;
  }
}

// ---------------- flash attention, barrier-free K-loop + rel prefetch ------
// grid (16, 64) remapped via bijective XCD swizzle: each XCD's 128 resident
// blocks cover 8 bh -> K/V (2 MB) stays L2-resident; fragments read straight
// from global (L2 hit); rel (HBM/L3 stream) register-prefetched one K-tile
// ahead so its latency hides under softmax+PV+next QK.
// q,k: bf16 [bh][n][64]; vt: bf16 [bh][dh][n]; rel fp32 [bh][n][n].
__global__ __launch_bounds__(256, 4) void attn_k(
    const unsigned short* __restrict__ q_ws, const unsigned short* __restrict__ k_ws,
    const unsigned short* __restrict__ vt_ws, const float* __restrict__ rel,
    const int* __restrict__ qmask, const int* __restrict__ cmask,
    unsigned short* __restrict__ aout) {
  constexpr float SCALE = 0.125f;  // 64^-0.5
  __shared__ alignas(16) unsigned short Pl[4 * 16 * 72];
  __shared__ float cml[1024];

  const int tid = threadIdx.x;
  const int w = tid >> 6, lane = tid & 63;
  const int quad = lane >> 4, lanelo = lane & 15;

  // XCD swizzle: flat in [0,1024); virt = (flat%8)*128 + flat/8 (bijective).
  const int flat = blockIdx.y * 16 + blockIdx.x;
  const int virt = (flat & 7) * 128 + (flat >> 3);
  const int bh = virt >> 4, qblk = virt & 15;
  const int b_ = bh >> 4, h = bh & 15;
  const int qrow0 = qblk * 64 + w * 16;

  for (int i = tid; i < 1024; i += 256)
    cml[i] = (cmask[b_ * 1024 + i] != 0) ? 1.f : 0.f;
  __syncthreads();   // the only block-wide barrier

  const unsigned short* qg = q_ws + ((size_t)bh * 1024 + qrow0) * 64;
  short8 qf0 = *(const short8*)(qg + (size_t)lanelo * 64 + quad * 8);
  short8 qf1 = *(const short8*)(qg + (size_t)lanelo * 64 + 32 + quad * 8);

  float qmv[4];
#pragma unroll
  for (int r = 0; r < 4; ++r)
    qmv[r] = (qmask[b_ * 1024 + qrow0 + quad * 4 + r] != 0) ? 1.f : 0.f;

  f32x4 o[4];
#pragma unroll
  for (int g = 0; g < 4; ++g) o[g] = (f32x4){0.f, 0.f, 0.f, 0.f};
  float m_run[4], l_run[4];
#pragma unroll
  for (int r = 0; r < 4; ++r) { m_run[r] = -NEGMAX; l_run[r] = 0.f; }

  const unsigned short* kg = k_ws + (size_t)bh * 65536;
  const unsigned short* vg = vt_ws + (size_t)bh * 65536;
  const float* relg = rel + ((size_t)bh * 1024 + qrow0) * 1024;
  unsigned short* pw = Pl + w * 16 * 72;

  // rel prefetch for kb=0
  float rl[4][4];
#pragma unroll
  for (int r = 0; r < 4; ++r)
#pragma unroll
    for (int c = 0; c < 4; ++c)
      rl[r][c] = relg[(size_t)(quad * 4 + r) * 1024 + c * 16 + lanelo];

  for (int kb = 0; kb < 16; ++kb) {
    const int key0 = kb * 64;

    // S = Q K^T : 16 q-rows x 64 keys; K fragments straight from L2.
    f32x4 s[4];
#pragma unroll
    for (int c = 0; c < 4; ++c) {
      const unsigned short* krow = kg + (size_t)(key0 + c * 16 + lanelo) * 64;
      short8 kfa = *(const short8*)(krow + quad * 8);
      short8 kfb = *(const short8*)(krow + 32 + quad * 8);
      s[c] = (f32x4){0.f, 0.f, 0.f, 0.f};
      s[c] = __builtin_amdgcn_mfma_f32_16x16x32_bf16(qf0, kfa, s[c], 0, 0, 0);
      s[c] = __builtin_amdgcn_mfma_f32_16x16x32_bf16(qf1, kfb, s[c], 0, 0, 0);
    }

    // prefetch next tile's rel while MFMAs / softmax run (issued now, used
    // next iteration -> ~full-iteration latency cover)
    float rln[4][4];
    if (kb + 1 < 16) {
#pragma unroll
      for (int r = 0; r < 4; ++r)
#pragma unroll
        for (int c = 0; c < 4; ++c)
          rln[r][c] = relg[(size_t)(quad * 4 + r) * 1024 + key0 + 64 + c * 16 + lanelo];
    }

    float cm[4];
#pragma unroll
    for (int c = 0; c < 4; ++c) cm[c] = cml[key0 + c * 16 + lanelo];

#pragma unroll
    for (int r = 0; r < 4; ++r) {
      const bool qok = qmv[r] != 0.f;
      float x[4], mloc = -NEGMAX;
#pragma unroll
      for (int c = 0; c < 4; ++c) {
        x[c] = (qok && cm[c] != 0.f) ? s[c][r] * SCALE + rl[r][c] : -NEGMAX;
        mloc = fmaxf(mloc, x[c]);
      }
      for (int off = 1; off < 16; off <<= 1) mloc = fmaxf(mloc, __shfl_xor(mloc, off));
      float mnew = fmaxf(m_run[r], mloc);
      float alpha = __expf(m_run[r] - mnew);
      m_run[r] = mnew;
      float ps = 0.f;
      unsigned short pb[4];
#pragma unroll
      for (int c = 0; c < 4; ++c) {
        float p = __expf(x[c] - mnew);
        ps += p;
        pb[c] = f2bf(p);
      }
      for (int off = 1; off < 16; off <<= 1) ps += __shfl_xor(ps, off);
      l_run[r] = l_run[r] * alpha + ps;
#pragma unroll
      for (int g = 0; g < 4; ++g) o[g][r] *= alpha;
#pragma unroll
      for (int c = 0; c < 4; ++c) pw[(quad * 4 + r) * 72 + c * 16 + lanelo] = pb[c];
    }

    if (kb + 1 < 16) {
#pragma unroll
      for (int r = 0; r < 4; ++r)
#pragma unroll
        for (int c = 0; c < 4; ++c) rl[r][c] = rln[r][c];
    }

    // P (A-layout via per-wave LDS transpose; within-wave, no barrier needed)
    // @ V, V fragments straight from L2, two k=32 chunks.
#pragma unroll
    for (int c2 = 0; c2 < 2; ++c2) {
      short8 pa = *(const short8*)((const char*)pw + lanelo * 144 + c2 * 64 + quad * 16);
#pragma unroll
      for (int g = 0; g < 4; ++g) {
        short8 vb = *(const short8*)(vg + (size_t)(g * 16 + lanelo) * 1024 + key0 + c2 * 32 + quad * 8);
        o[g] = __builtin_amdgcn_mfma_f32_16x16x32_bf16(pa, vb, o[g], 0, 0, 0);
      }
    }
  }

#pragma unroll
  for (int r = 0; r < 4; ++r) {
    float inv = 1.f / l_run[r];
    size_t row = (size_t)(b_ * 1024 + qrow0 + quad * 4 + r) * 1024;
#pragma unroll
    for (int g = 0; g < 4; ++g)
      aout[row + h * 64 + g * 16 + lanelo] = f2bf(o[g][r] * inv);
  }
}

// ---------------- launch ----------------------------------------------------
extern "C" void kernel_launch(void* const* d_in, const int* in_sizes, int n_in,
                              void* d_out, int out_size, void* d_ws, size_t ws_size,
                              hipStream_t stream) {
  const float* x = (const float*)d_in[0];
  const float* rel = (const float*)d_in[1];
  const int* qmask = (const int*)d_in[2];
  const int* cmask = (const int*)d_in[3];
  const float* Wq = (const float*)d_in[4];
  const float* Wkv = (const float*)d_in[5];
  const float* Wo = (const float*)d_in[6];
  const float* bo = (const float*)d_in[7];
  float* out = (float*)d_out;

  char* ws = (char*)d_ws;
  const size_t MB = 1024 * 1024;
  unsigned short* w3t = (unsigned short*)(ws);            // 3072x1024 bf16 (6 MB)
  unsigned short* wot = (unsigned short*)(ws + 6 * MB);   // 1024x1024 bf16 (2 MB)
  unsigned short* xb  = (unsigned short*)(ws + 8 * MB);   // 4096x1024 bf16 (8 MB)
  unsigned short* qws = (unsigned short*)(ws + 16 * MB);  // [bh][n][64] (8 MB)
  unsigned short* kws = (unsigned short*)(ws + 24 * MB);  // 8 MB
  unsigned short* vtws = (unsigned short*)(ws + 32 * MB); // [bh][dh][n] (8 MB)
  unsigned short* aout = xb;  // reuse: x dead after QKV GEMM

  cast_x_k<<<4096, 256, 0, stream>>>(x, xb);
  tcast_k<<<dim3(16, 16), 256, 0, stream>>>(Wq, 1024, w3t);
  tcast_k<<<dim3(32, 16), 256, 0, stream>>>(Wkv, 2048, w3t + (size_t)1024 * 1024);
  tcast_k<<<dim3(16, 16), 256, 0, stream>>>(Wo, 1024, wot);
  gemm_bt_k<<<dim3(24, 32), 256, 0, stream>>>(xb, w3t, qws, kws, vtws);
  attn_k<<<dim3(16, 64), 256, 0, stream>>>(qws, kws, vtws, rel, qmask, cmask, aout);
  gemm64_k<<<dim3(16, 64), 256, 0, stream>>>(aout, wot, bo, out);
}

// Round 3
// 487.602 us; speedup vs baseline: 1.1281x; 1.0697x over previous
//
#include <hip/hip_runtime.h>

// ---------------------------------------------------------------------------
// Attention_49185965474367: B=4, N=1024, D=1024, H=16, DH=64, INNER=1024
// R5: attn latency fix: amdgpu_waves_per_eu(4,4) (stop compiler targeting the
//     64-VGPR/8-wave bucket and sinking prefetches), K-tile via double-buffered
//     global_load_lds DMA (swizzled src+read, 1 barrier/iter), V frags hoisted
//     into regs at top of iteration, rel single-buffer reg prefetch.
// ---------------------------------------------------------------------------

#define NEGMAX 3.402823466e+38f

typedef short short8 __attribute__((ext_vector_type(8)));
typedef float f32x4 __attribute__((ext_vector_type(4)));

__device__ __forceinline__ unsigned short f2bf(float f) {
  unsigned int u = __float_as_uint(f);
  u += 0x7FFFu + ((u >> 16) & 1u);   // round-to-nearest-even
  return (unsigned short)(u >> 16);
}

// async global->LDS, 16B per lane. lds_base must be wave-uniform; HW scatters
// lane i to lds_base + i*16. Global src addr IS per-lane (guide §5).
__device__ __forceinline__ void stage16(const void* g, void* lds_base, int lane) {
#if __has_builtin(__builtin_amdgcn_global_load_lds)
  __builtin_amdgcn_global_load_lds(
      (const __attribute__((address_space(1))) unsigned int*)g,
      (__attribute__((address_space(3))) unsigned int*)lds_base, 16, 0, 0);
#else
  *(int4*)((char*)lds_base + lane * 16) = *(const int4*)g;
#endif
}

// ---------------- cast kernels ---------------------------------------------
__global__ void cast_x_k(const float* __restrict__ x, unsigned short* __restrict__ xb) {
  int i = (blockIdx.x * 256 + threadIdx.x) * 4;
  float4 v = *(const float4*)(x + i);
  ushort4 o;
  o.x = f2bf(v.x); o.y = f2bf(v.y); o.z = f2bf(v.z); o.w = f2bf(v.w);
  *(ushort4*)(xb + i) = o;
}

// dst[n][d] = src[d][n]  (src fp32 [1024 x ldsrc], dst bf16 rows of 1024)
__global__ __launch_bounds__(256) void tcast_k(const float* __restrict__ src, int ldsrc,
                                               unsigned short* __restrict__ dst) {
  __shared__ float T[64][65];
  const int n0 = blockIdx.x * 64, d0 = blockIdx.y * 64;
  const int tx = threadIdx.x & 63, ty = threadIdx.x >> 6;
#pragma unroll
  for (int k = 0; k < 16; ++k) {
    int dl = k * 4 + ty;
    T[dl][tx] = src[(size_t)(d0 + dl) * ldsrc + n0 + tx];
  }
  __syncthreads();
#pragma unroll
  for (int k = 0; k < 16; ++k) {
    int nl = k * 4 + ty;
    dst[(size_t)(n0 + nl) * 1024 + d0 + tx] = f2bf(T[tx][nl]);
  }
}

// ---------------- GEMM: C[M,N] = A[M,K] @ Bt[N,K]^T  (bf16 in, fp32 acc) ---
// 128x128 tile, BK=32, 256 threads (4 waves), global_load_lds staging (m97).
// QKV projection with scattered head-layout epilogue.
__global__ __launch_bounds__(256) void gemm_bt_k(
    const unsigned short* __restrict__ A, const unsigned short* __restrict__ Bt,
    unsigned short* __restrict__ qws, unsigned short* __restrict__ kws,
    unsigned short* __restrict__ vtws) {
  constexpr int K = 1024;
  constexpr int NKB = K / 32;
  __shared__ alignas(16) unsigned short As[128 * 32];
  __shared__ alignas(16) unsigned short Bs[128 * 32];
  const int tid = threadIdx.x;
  const int lane = tid & 63, w = tid >> 6;
  const int quad = lane >> 4, lanelo = lane & 15;
  const int tRow = blockIdx.y * 128, tCol = blockIdx.x * 128;
  const int wr = (w >> 1) * 64, wc = (w & 1) * 64;
  const char* AgB = (const char*)(A + (size_t)tRow * K);
  const char* BgB = (const char*)(Bt + (size_t)tCol * K);
  const int c0 = tid, c1 = tid + 256;
  const size_t a0off = (size_t)(c0 >> 2) * 2048 + (c0 & 3) * 16;
  const size_t a1off = (size_t)(c1 >> 2) * 2048 + (c1 & 3) * 16;
  char* ldsA0 = (char*)As + w * 1024;
  char* ldsA1 = (char*)As + 4096 + w * 1024;
  char* ldsB0 = (char*)Bs + w * 1024;
  char* ldsB1 = (char*)Bs + 4096 + w * 1024;

  f32x4 acc[4][4];
#pragma unroll
  for (int i = 0; i < 4; ++i)
#pragma unroll
    for (int j = 0; j < 4; ++j) acc[i][j] = (f32x4){0.f, 0.f, 0.f, 0.f};

  for (int kb = 0; kb < NKB; ++kb) {
    if (kb) __syncthreads();
    const size_t ko = (size_t)kb * 64;
    stage16(AgB + a0off + ko, ldsA0, lane);
    stage16(AgB + a1off + ko, ldsA1, lane);
    stage16(BgB + a0off + ko, ldsB0, lane);
    stage16(BgB + a1off + ko, ldsB1, lane);
    __syncthreads();   // drains vmcnt before any frag read

    short8 af[4], bf[4];
#pragma unroll
    for (int i = 0; i < 4; ++i)
      af[i] = *(const short8*)(As + (wr + i * 16 + lanelo) * 32 + quad * 8);
#pragma unroll
    for (int j = 0; j < 4; ++j)
      bf[j] = *(const short8*)(Bs + (wc + j * 16 + lanelo) * 32 + quad * 8);
#pragma unroll
    for (int i = 0; i < 4; ++i)
#pragma unroll
      for (int j = 0; j < 4; ++j)
        acc[i][j] = __builtin_amdgcn_mfma_f32_16x16x32_bf16(af[i], bf[j], acc[i][j], 0, 0, 0);
  }

#pragma unroll
  for (int i = 0; i < 4; ++i) {
    int row = tRow + wr + i * 16 + quad * 4;
    int b_ = row >> 10;
    int npos = row & 1023;
#pragma unroll
    for (int j = 0; j < 4; ++j) {
      int col = tCol + wc + j * 16 + lanelo;
      if (col < 2048) {
        unsigned short* dst = (col < 1024) ? qws : kws;
        int c = col & 1023;
        int hh = c >> 6, dh = c & 63;
        size_t base = ((size_t)(b_ * 16 + hh) * 1024 + npos) * 64 + dh;
#pragma unroll
        for (int r = 0; r < 4; ++r) dst[base + (size_t)r * 64] = f2bf(acc[i][j][r]);
      } else {
        int c = col - 2048;
        ushort4 pk;
        pk.x = f2bf(acc[i][j][0]);
        pk.y = f2bf(acc[i][j][1]);
        pk.z = f2bf(acc[i][j][2]);
        pk.w = f2bf(acc[i][j][3]);
        *(ushort4*)&vtws[((size_t)(b_ * 16 + (c >> 6)) * 64 + (c & 63)) * 1024 + npos] = pk;
      }
    }
  }
}

// ---------------- GEMM 64x64: C = A @ Bt^T + bias  (out projection) --------
// 1024 blocks (4/CU), 256 thr = 4 waves; wave w owns rows [w*16, w*16+16).
__global__ __launch_bounds__(256) void gemm64_k(
    const unsigned short* __restrict__ A, const unsigned short* __restrict__ Bt,
    const float* __restrict__ bias, float* __restrict__ Cout) {
  constexpr int K = 1024;
  constexpr int NKB = K / 32;
  __shared__ alignas(16) unsigned short As[64 * 32];
  __shared__ alignas(16) unsigned short Bs[64 * 32];
  const int tid = threadIdx.x;
  const int lane = tid & 63, w = tid >> 6;
  const int quad = lane >> 4, lanelo = lane & 15;
  const int tRow = blockIdx.y * 64, tCol = blockIdx.x * 64;
  const char* AgB = (const char*)(A + (size_t)tRow * K);
  const char* BgB = (const char*)(Bt + (size_t)tCol * K);
  const size_t aoff = (size_t)(tid >> 2) * 2048 + (tid & 3) * 16;
  char* ldsA = (char*)As + w * 1024;
  char* ldsB = (char*)Bs + w * 1024;

  f32x4 acc[4];
#pragma unroll
  for (int j = 0; j < 4; ++j) acc[j] = (f32x4){0.f, 0.f, 0.f, 0.f};

  for (int kb = 0; kb < NKB; ++kb) {
    if (kb) __syncthreads();
    const size_t ko = (size_t)kb * 64;
    stage16(AgB + aoff + ko, ldsA, lane);
    stage16(BgB + aoff + ko, ldsB, lane);
    __syncthreads();

    short8 af = *(const short8*)(As + (w * 16 + lanelo) * 32 + quad * 8);
#pragma unroll
    for (int j = 0; j < 4; ++j) {
      short8 bf = *(const short8*)(Bs + (j * 16 + lanelo) * 32 + quad * 8);
      acc[j] = __builtin_amdgcn_mfma_f32_16x16x32_bf16(af, bf, acc[j], 0, 0, 0);
    }
  }

  const int row = tRow + w * 16 + quad * 4;
#pragma unroll
  for (int j = 0; j < 4; ++j) {
    int col = tCol + j * 16 + lanelo;
    float bv = bias[col];
#pragma unroll
    for (int r = 0; r < 4; ++r)
      Cout[(size_t)(row + r) * 1024 + col] = acc[j][r] + bv;
  }
}

// ---------------- flash attention, K via LDS-DMA double buffer -------------
// grid (16, 64) XCD-swizzled (8 bh per XCD -> K/V L2-resident).
// Per K-tile: 1 barrier; K[kb+1] DMA'd global->LDS (swizzled src, linear
// dest); V frags reg-hoisted at top (cover = QK+softmax); rel reg-prefetched
// post-softmax (cover = PV + barrier drain).
// q,k: bf16 [bh][n][64]; vt: bf16 [bh][dh][n]; rel fp32 [bh][n][n].
__global__ __launch_bounds__(256)
__attribute__((amdgpu_waves_per_eu(4, 4)))
void attn_k(
    const unsigned short* __restrict__ q_ws, const unsigned short* __restrict__ k_ws,
    const unsigned short* __restrict__ vt_ws, const float* __restrict__ rel,
    const int* __restrict__ qmask, const int* __restrict__ cmask,
    unsigned short* __restrict__ aout) {
  constexpr float SCALE = 0.125f;  // 64^-0.5
  __shared__ alignas(16) unsigned short Kl[2 * 64 * 64];   // 2 x 8KB, linear (DMA dest)
  __shared__ alignas(16) unsigned short Pl[4 * 16 * 72];
  __shared__ float cml[1024];

  const int tid = threadIdx.x;
  const int w = tid >> 6, lane = tid & 63;
  const int quad = lane >> 4, lanelo = lane & 15;

  // XCD swizzle: flat in [0,1024); virt = (flat%8)*128 + flat/8 (bijective).
  const int flat = blockIdx.y * 16 + blockIdx.x;
  const int virt = (flat & 7) * 128 + (flat >> 3);
  const int bh = virt >> 4, qblk = virt & 15;
  const int b_ = bh >> 4, h = bh & 15;
  const int qrow0 = qblk * 64 + w * 16;

  const unsigned short* kg = k_ws + (size_t)bh * 65536;
  const unsigned short* vg = vt_ws + (size_t)bh * 65536;
  const float* relg = rel + ((size_t)bh * 1024 + qrow0) * 1024;
  unsigned short* pw = Pl + w * 16 * 72;

  // DMA one 64-key K tile into Kl[buf]. LDS dest linear; global src carries
  // the inverse of the read-side XOR swizzle (piece p holds logical piece
  // p ^ (row&7)) so reads can de-conflict banks (rule #21).
  const int srow = lane >> 3;            // row-within-8 handled per issue
  const int sp = lane & 7;
  const int spx = ((sp ^ srow) << 4);    // swizzled 16B piece offset
#define STAGE_K(buf, key0n)                                                     \
  {                                                                             \
    _Pragma("unroll")                                                           \
    for (int i_ = 0; i_ < 2; ++i_) {                                            \
      int row_ = w * 16 + i_ * 8 + srow;                                        \
      stage16((const char*)kg + (size_t)((key0n) + row_) * 128 + spx,           \
              (char*)Kl + (buf) * 8192 + w * 2048 + i_ * 1024, lane);           \
    }                                                                           \
  }

  STAGE_K(0, 0);   // K[0] -> buf0 (issued before anything else)

  for (int i = tid; i < 1024; i += 256)
    cml[i] = (cmask[b_ * 1024 + i] != 0) ? 1.f : 0.f;

  const unsigned short* qg = q_ws + ((size_t)bh * 1024 + qrow0) * 64;
  short8 qf0 = *(const short8*)(qg + (size_t)lanelo * 64 + quad * 8);
  short8 qf1 = *(const short8*)(qg + (size_t)lanelo * 64 + 32 + quad * 8);

  float qmv[4];
#pragma unroll
  for (int r = 0; r < 4; ++r)
    qmv[r] = (qmask[b_ * 1024 + qrow0 + quad * 4 + r] != 0) ? 1.f : 0.f;

  f32x4 o[4];
#pragma unroll
  for (int g = 0; g < 4; ++g) o[g] = (f32x4){0.f, 0.f, 0.f, 0.f};
  float m_run[4], l_run[4];
#pragma unroll
  for (int r = 0; r < 4; ++r) { m_run[r] = -NEGMAX; l_run[r] = 0.f; }

  // rel prefetch for kb=0
  float rl[4][4];
#pragma unroll
  for (int r = 0; r < 4; ++r)
#pragma unroll
    for (int c = 0; c < 4; ++c)
      rl[r][c] = relg[(size_t)(quad * 4 + r) * 1024 + c * 16 + lanelo];

  const int sb = lanelo & 7;             // read-side swizzle key (row&7)

  for (int kb = 0; kb < 16; ++kb) {
    const int key0 = kb * 64;
    const int cur = kb & 1;

    // K[kb] DMA (issued last iter / prologue) completes at this barrier
    // (each wave drains its own vmcnt); also closes WAR on Kl[cur^1].
    __syncthreads();

    if (kb + 1 < 16) STAGE_K(cur ^ 1, key0 + 64);

    // hoist V frags for THIS tile into regs: cover = QK + softmax (~600cy)
    short8 vf[8];
#pragma unroll
    for (int c2 = 0; c2 < 2; ++c2)
#pragma unroll
      for (int g = 0; g < 4; ++g)
        vf[c2 * 4 + g] = *(const short8*)(vg + (size_t)(g * 16 + lanelo) * 1024 +
                                          key0 + c2 * 32 + quad * 8);

    // S = Q K^T : K frags from LDS (swizzled read; 2-way conflict max)
    f32x4 s[4];
#pragma unroll
    for (int c = 0; c < 4; ++c) {
      const char* kbase = (const char*)Kl + cur * 8192 + (c * 16 + lanelo) * 128;
      short8 kfa = *(const short8*)(kbase + ((quad ^ sb) << 4));
      short8 kfb = *(const short8*)(kbase + (((4 + quad) ^ sb) << 4));
      s[c] = (f32x4){0.f, 0.f, 0.f, 0.f};
      s[c] = __builtin_amdgcn_mfma_f32_16x16x32_bf16(qf0, kfa, s[c], 0, 0, 0);
      s[c] = __builtin_amdgcn_mfma_f32_16x16x32_bf16(qf1, kfb, s[c], 0, 0, 0);
    }

    float cm[4];
#pragma unroll
    for (int c = 0; c < 4; ++c) cm[c] = cml[key0 + c * 16 + lanelo];

#pragma unroll
    for (int r = 0; r < 4; ++r) {
      const bool qok = qmv[r] != 0.f;
      float x[4], mloc = -NEGMAX;
#pragma unroll
      for (int c = 0; c < 4; ++c) {
        x[c] = (qok && cm[c] != 0.f) ? s[c][r] * SCALE + rl[r][c] : -NEGMAX;
        mloc = fmaxf(mloc, x[c]);
      }
      for (int off = 1; off < 16; off <<= 1) mloc = fmaxf(mloc, __shfl_xor(mloc, off));
      float mnew = fmaxf(m_run[r], mloc);
      float alpha = __expf(m_run[r] - mnew);
      m_run[r] = mnew;
      float ps = 0.f;
      unsigned short pb[4];
#pragma unroll
      for (int c = 0; c < 4; ++c) {
        float p = __expf(x[c] - mnew);
        ps += p;
        pb[c] = f2bf(p);
      }
      for (int off = 1; off < 16; off <<= 1) ps += __shfl_xor(ps, off);
      l_run[r] = l_run[r] * alpha + ps;
#pragma unroll
      for (int g = 0; g < 4; ++g) o[g][r] *= alpha;
#pragma unroll
      for (int c = 0; c < 4; ++c) pw[(quad * 4 + r) * 72 + c * 16 + lanelo] = pb[c];
    }

    // prefetch next tile's rel (consumed next iteration; drained at barrier)
    if (kb + 1 < 16) {
#pragma unroll
      for (int r = 0; r < 4; ++r)
#pragma unroll
        for (int c = 0; c < 4; ++c)
          rl[r][c] = relg[(size_t)(quad * 4 + r) * 1024 + key0 + 64 + c * 16 + lanelo];
    }

    // P (per-wave LDS transpose, within-wave order) @ V from regs
#pragma unroll
    for (int c2 = 0; c2 < 2; ++c2) {
      short8 pa = *(const short8*)((const char*)pw + lanelo * 144 + c2 * 64 + quad * 16);
#pragma unroll
      for (int g = 0; g < 4; ++g)
        o[g] = __builtin_amdgcn_mfma_f32_16x16x32_bf16(pa, vf[c2 * 4 + g], o[g], 0, 0, 0);
    }
  }
#undef STAGE_K

#pragma unroll
  for (int r = 0; r < 4; ++r) {
    float inv = 1.f / l_run[r];
    size_t row = (size_t)(b_ * 1024 + qrow0 + quad * 4 + r) * 1024;
#pragma unroll
    for (int g = 0; g < 4; ++g)
      aout[row + h * 64 + g * 16 + lanelo] = f2bf(o[g][r] * inv);
  }
}

// ---------------- launch ----------------------------------------------------
extern "C" void kernel_launch(void* const* d_in, const int* in_sizes, int n_in,
                              void* d_out, int out_size, void* d_ws, size_t ws_size,
                              hipStream_t stream) {
  const float* x = (const float*)d_in[0];
  const float* rel = (const float*)d_in[1];
  const int* qmask = (const int*)d_in[2];
  const int* cmask = (const int*)d_in[3];
  const float* Wq = (const float*)d_in[4];
  const float* Wkv = (const float*)d_in[5];
  const float* Wo = (const float*)d_in[6];
  const float* bo = (const float*)d_in[7];
  float* out = (float*)d_out;

  char* ws = (char*)d_ws;
  const size_t MB = 1024 * 1024;
  unsigned short* w3t = (unsigned short*)(ws);            // 3072x1024 bf16 (6 MB)
  unsigned short* wot = (unsigned short*)(ws + 6 * MB);   // 1024x1024 bf16 (2 MB)
  unsigned short* xb  = (unsigned short*)(ws + 8 * MB);   // 4096x1024 bf16 (8 MB)
  unsigned short* qws = (unsigned short*)(ws + 16 * MB);  // [bh][n][64] (8 MB)
  unsigned short* kws = (unsigned short*)(ws + 24 * MB);  // 8 MB
  unsigned short* vtws = (unsigned short*)(ws + 32 * MB); // [bh][dh][n] (8 MB)
  unsigned short* aout = xb;  // reuse: x dead after QKV GEMM

  cast_x_k<<<4096, 256, 0, stream>>>(x, xb);
  tcast_k<<<dim3(16, 16), 256, 0, stream>>>(Wq, 1024, w3t);
  tcast_k<<<dim3(32, 16), 256, 0, stream>>>(Wkv, 2048, w3t + (size_t)1024 * 1024);
  tcast_k<<<dim3(16, 16), 256, 0, stream>>>(Wo, 1024, wot);
  gemm_bt_k<<<dim3(24, 32), 256, 0, stream>>>(xb, w3t, qws, kws, vtws);
  attn_k<<<dim3(16, 64), 256, 0, stream>>>(qws, kws, vtws, rel, qmask, cmask, aout);
  gemm64_k<<<dim3(16, 64), 256, 0, stream>>>(aout, wot, bo, out);
}